// Round 4
// baseline (544.768 us; speedup 1.0000x reference)
//
#include <hip/hip_runtime.h>

#define P 8192
#define ITERS 10
#define NB 2048      // OpenBLAS sgemv_t_4.c NBMAX (dot-length blocking)
#define NBP 2056     // LDS chunk stride (pad 8 floats -> conflict-free banks)

// Bit-exact emulation of numpy f32 tanh(W @ s) with OpenBLAS sgemv_t
// (Haswell/Zen microkernel), per output row j:
//   for chunk c in 0..3 (NBMAX=2048 blocks of the dot length):
//     8 accumulator chains: lane l accumulates elements i == l (mod 8),
//     increasing i, sequential single-rounded FMA (vfmadd231ps, 2x per ymm
//     per 16-element iteration == one stride-8 chain)
//     reduce: v_l = acc_l + acc_{l+4}; d_c = (v0+v1)+(v2+v3)   (vhaddps x2)
//   y_j = (((d0 + d1) + d2) + d3)        (per-block y accumulation, alpha=1)
// then tanh (device tanhf vs numpy tanhf: few-ulp, under threshold after
// chaotic amplification).
__global__ __launch_bounds__(256) void hopfield_openblas_gemv_tanh(
    const float* __restrict__ W,
    const float* __restrict__ s,
    float* __restrict__ y)
{
    __shared__ float xs[4 * NBP];

    const int t = threadIdx.x;

    // stage state into LDS; +8-float pad per 2048-chunk spreads the
    // (c,l) read pattern across all 32 banks (2056 % 32 == 8)
    for (int i = t * 4; i < P; i += 256 * 4) {
        float4 v = *reinterpret_cast<const float4*>(s + i);
        *reinterpret_cast<float4*>(&xs[(i >> 11) * NBP + (i & (NB - 1))]) = v;
    }
    __syncthreads();

    const int half = t >> 5;           // 8 half-waves -> 8 rows per block
    const int w    = t & 31;
    const int c    = w >> 3;           // NBMAX chunk 0..3
    const int l    = w & 7;            // ymm lane = mod-8 chain

    const int row = blockIdx.x * 8 + half;
    const float* __restrict__ Wp = W + (size_t)row * P + c * NB + l;
    const float* __restrict__ xp = &xs[c * NBP + l];

    float acc = 0.0f;
#pragma unroll 16
    for (int k = 0; k < NB / 8; ++k)
        acc = fmaf(Wp[8 * k], xp[8 * k], acc);

    // vextractf128 + vaddps: v_l = acc_l + acc_{l+4}
    float v = acc + __shfl_down(acc, 4, 8);
    // vhaddps twice: ((v0+v1) + (v2+v3))
    float h = v + __shfl_down(v, 1, 8);
    float d = h + __shfl_down(h, 2, 8);

    // chunk partials added to y in increasing-chunk order (left-assoc)
    float d1 = __shfl_down(d, 8, 32);
    float d2 = __shfl_down(d, 16, 32);
    float d3 = __shfl_down(d, 24, 32);

    if (w == 0)
        y[row] = tanhf(((d + d1) + d2) + d3);
}

extern "C" void kernel_launch(void* const* d_in, const int* in_sizes, int n_in,
                              void* d_out, int out_size, void* d_ws, size_t ws_size,
                              hipStream_t stream)
{
    const float* x = (const float*)d_in[0];
    const float* W = (const float*)d_in[1];
    float* out = (float*)d_out;

    float* s0 = (float*)d_ws;        // 32 KiB ping
    float* s1 = s0 + P;              // 32 KiB pong

    const float* src = x;
    for (int it = 0; it < ITERS; ++it) {
        float* dst = (it == ITERS - 1) ? out : ((it & 1) ? s1 : s0);
        hipLaunchKernelGGL(hopfield_openblas_gemv_tanh,
                           dim3(P / 8), dim3(256), 0, stream,
                           W, src, dst);
        src = dst;
    }
}

// Round 5
// 458.132 us; speedup vs baseline: 1.1891x; 1.1891x over previous
//
#include <hip/hip_runtime.h>

#define P 8192
#define ITERS 10
#define NB 2048      // OpenBLAS sgemv_t NBMAX (dot-length blocking)
#define NBP 2056     // LDS chunk stride (+8 floats -> conflict-free banks)

// Bit-exact OpenBLAS sgemv_t (Haswell/Zen) emulation, vectorized loads.
// Per output row j, chunk c (2048 elems): 8 mod-8 FMA chains, reduced as
//   v_l = acc_l + acc_{l+4};  d_c = (v0+v1)+(v2+v3)
// then y_j = ((d0+d1)+d2)+d3, then tanh.
// Here one lane owns FOUR chains (half-octet ho): float4 W/x loads feed 4
// separate accumulators -> identical per-chain content and order as the
// scalar version (round 4, passed), 4x fewer vmem instructions, 16B/lane.
__global__ __launch_bounds__(64) void hopfield_openblas_gemv_tanh(
    const float* __restrict__ W,
    const float* __restrict__ s,
    float* __restrict__ y)
{
    __shared__ float xs[4 * NBP];

    const int t = threadIdx.x;   // 0..63, one wave per block

    // stage state into LDS (padded per 2048-chunk), coalesced float4
    for (int i = t * 4; i < P; i += 64 * 4) {
        float4 v = *reinterpret_cast<const float4*>(s + i);
        *reinterpret_cast<float4*>(&xs[(i >> 11) * NBP + (i & (NB - 1))]) = v;
    }
    __syncthreads();

    const int row_sub = t >> 3;        // 8 rows per wave
    const int c       = (t >> 1) & 3;  // NBMAX chunk 0..3
    const int ho      = t & 1;         // half-octet: chains 4ho..4ho+3

    const int row = blockIdx.x * 8 + row_sub;
    const float* __restrict__ Wp = W + (size_t)row * P + c * NB + 4 * ho;
    const float* __restrict__ xp = &xs[c * NBP + 4 * ho];

    float a0 = 0.0f, a1 = 0.0f, a2 = 0.0f, a3 = 0.0f;
#pragma unroll 8
    for (int k = 0; k < NB / 8; ++k) {
        float4 w4 = *reinterpret_cast<const float4*>(Wp + 8 * k);
        float4 x4 = *reinterpret_cast<const float4*>(xp + 8 * k);
        a0 = fmaf(w4.x, x4.x, a0);   // chain 4ho+0, step k
        a1 = fmaf(w4.y, x4.y, a1);   // chain 4ho+1
        a2 = fmaf(w4.z, x4.z, a2);   // chain 4ho+2
        a3 = fmaf(w4.w, x4.w, a3);   // chain 4ho+3
    }

    // v_l = acc_l + acc_{l+4}  (ho=0 lane + ho=1 lane, lane pairs)
    float v0 = a0 + __shfl_down(a0, 1, 2);
    float v1 = a1 + __shfl_down(a1, 1, 2);
    float v2 = a2 + __shfl_down(a2, 1, 2);
    float v3 = a3 + __shfl_down(a3, 1, 2);
    // vhaddps x2: (v0+v1)+(v2+v3)
    float d = (v0 + v1) + (v2 + v3);

    // chunk partials, increasing-chunk left-associative (8-lane row group)
    float d1 = __shfl_down(d, 2, 8);
    float d2 = __shfl_down(d, 4, 8);
    float d3 = __shfl_down(d, 6, 8);

    if ((t & 7) == 0)
        y[row] = tanhf(((d + d1) + d2) + d3);
}

extern "C" void kernel_launch(void* const* d_in, const int* in_sizes, int n_in,
                              void* d_out, int out_size, void* d_ws, size_t ws_size,
                              hipStream_t stream)
{
    const float* x = (const float*)d_in[0];
    const float* W = (const float*)d_in[1];
    float* out = (float*)d_out;

    float* s0 = (float*)d_ws;        // 32 KiB ping
    float* s1 = s0 + P;              // 32 KiB pong

    const float* src = x;
    for (int it = 0; it < ITERS; ++it) {
        float* dst = (it == ITERS - 1) ? out : ((it & 1) ? s1 : s0);
        hipLaunchKernelGGL(hopfield_openblas_gemv_tanh,
                           dim3(P / 8), dim3(64), 0, stream,
                           W, src, dst);
        src = dst;
    }
}